// Round 1
// baseline (299.905 us; speedup 1.0000x reference)
//
#include <hip/hip_runtime.h>

// Shapes: B=1, S=128, Q=256, C=256, H=8, DH=32, TOT=256. Inputs/out f32.
// Numerics bit-identical to R2-R7 (absmax 0.01953125 vs thr 0.019609).
// R8: attn occupancy push. Pl is wave-private -> chunk PV over k in 4 phases
// reusing a [4][16][76] buffer (LDS 52.2KB -> 27.6KB, 3 -> 5 blocks/CU).
// bias_pair pre-permuted to f32 [(h,qt,w)][nt][lane][rr] in prep so the attn
// bias add is 16 coalesced float4 loads/lane instead of 64 scalar L2 loads.
// qt tiles paired per block (grid 1024x2) to amortize Vt staging.

typedef unsigned short u16;
typedef unsigned int   u32;
typedef float  f32x4  __attribute__((ext_vector_type(4)));
typedef __bf16 bf16x8 __attribute__((ext_vector_type(8)));

__device__ __forceinline__ float bf2f(u16 u) {
    union { u32 i; float f; } v; v.i = ((u32)u) << 16; return v.f;
}
__device__ __forceinline__ u16 f2bf(float f) {      // hw RNE cvt
    __bf16 h = (__bf16)f; return __builtin_bit_cast(u16, h);
}

// async global->LDS, 16B/lane; lds dest wave-uniform base (HW adds lane*16)
__device__ __forceinline__ void gld16(const u16* g, u16* l) {
    __builtin_amdgcn_global_load_lds(
        (const __attribute__((address_space(1))) u32*)g,
        (__attribute__((address_space(3))) u32*)l, 16, 0, 0);
}

// head-major offset for logical (row = s*256+q, col = h*32+dh)
__device__ __forceinline__ size_t hm(int row, int col) {
    const int s = row >> 8, q = row & 255, h = col >> 5, dh = col & 31;
    return ((size_t)((h * 128 + s) * 256 + q) << 5) + dh;
}

// -------------------------------------------------------------------------
// prep: f32 -> bf16 for qx, kvx (into d_out scratch) and the 5 weight mats,
// plus f32 permute of bias_pair into bppf[(h,qt,w)][nt][lane][rr].
// -------------------------------------------------------------------------
__device__ __forceinline__ void cvt8(const float4* src, u16* dst) {
    float4 a = src[0], b = src[1];
    u16 r[8];
    r[0] = f2bf(a.x); r[1] = f2bf(a.y); r[2] = f2bf(a.z); r[3] = f2bf(a.w);
    r[4] = f2bf(b.x); r[5] = f2bf(b.y); r[6] = f2bf(b.z); r[7] = f2bf(b.w);
    *(uint4*)dst = *(uint4*)r;
}

__global__ __launch_bounds__(256) void prep(
    const float* __restrict__ qx, const float* __restrict__ kvx,
    const float* __restrict__ Wq, const float* __restrict__ Wk,
    const float* __restrict__ Wv, const float* __restrict__ Wg,
    const float* __restrict__ Wo, const float* __restrict__ bp,
    u16* __restrict__ Xq, u16* __restrict__ Xkv, u16* __restrict__ Wball,
    float* __restrict__ bppf)
{
    const int b = blockIdx.x, t = threadIdx.x;
    if (b < 4096) {
        const int e = (b * 256 + t) * 8;
        cvt8((const float4*)(qx + e), Xq + e);
    } else if (b < 8192) {
        const int e = ((b - 4096) * 256 + t) * 8;
        cvt8((const float4*)(kvx + e), Xkv + e);
    } else if (b < 8352) {
        const int b2  = b - 8192;            // 0..159: 32 blocks per matrix
        const int mat = b2 >> 5;
        const float* W = (mat == 0) ? Wq : (mat == 1) ? Wk : (mat == 2) ? Wv
                       : (mat == 3) ? Wg : Wo;
        const int off = (b2 & 31) * 2048 + t * 8;
        cvt8((const float4*)(W + off), Wball + mat * 65536 + off);
    } else {
        // bias_pair permute: unit u = ((h*4+qt)*4+w)*16*64 + nt*64 + lane,
        // holds bp rows q0..q0+3 (rr in float4 lanes) at col kp.
        const int b3 = b - 8352;             // 0..255
        const int u0 = (b3 * 256 + t) * 2;
        #pragma unroll
        for (int k2 = 0; k2 < 2; ++k2) {
            const int u  = u0 + k2;
            const int l  = u & 63;
            const int nt = (u >> 6) & 15;
            const int tt = u >> 10;          // (h*4+qt)*4+w, 0..127
            const int ww = tt & 3, qqt = (tt >> 2) & 3, hh = tt >> 4;
            const int qb = qqt * 64 + ww * 16 + (l >> 4) * 4;
            const int kp = nt * 16 + (l & 15);
            const float* src = bp + (size_t)(hh * 256 + qb) * 256 + kp;
            float4 v;
            v.x = src[0]; v.y = src[256]; v.z = src[512]; v.w = src[768];
            *(float4*)(bppf + (size_t)u * 4) = v;
        }
    }
}

// -------------------------------------------------------------------------
// proj_all: fused Q/K/V/G projections, m97 structure. 2048 blocks.
// Block tile 128x128, BK=64, 4 waves 2x2, wave 64x64 (4x4 frags).
// Swizzle: mb = bid&255 -> 8 A-sharing siblings 256 apart == same XCD.
// Output written HEAD-MAJOR via hm().
// -------------------------------------------------------------------------
__global__ __launch_bounds__(256) void proj_all(
    const u16* __restrict__ Xq, const u16* __restrict__ Xkv,
    const u16* __restrict__ Wball, const float* __restrict__ bg,
    u16* __restrict__ Qh, u16* __restrict__ Kh, u16* __restrict__ Vh, u16* __restrict__ Gh)
{
    __shared__ u16 At[128 * 64];     // unpadded: required by global_load_lds
    __shared__ u16 Wt[128 * 64];

    const int bid = blockIdx.x;
    const int mb  = bid & 255;
    const int nb  = bid >> 8;        // 0..7
    const int t   = nb >> 1;         // 0=Q 1=K 2=V 3=G
    const int n0  = (nb & 1) * 128;
    const int m0  = mb * 128;
    const u16* A = (t == 0 || t == 3) ? Xq : Xkv;
    const u16* W = Wball + t * 65536;
    u16*       O = (t == 0) ? Qh : (t == 1) ? Kh : (t == 2) ? Vh : Gh;

    const int tid  = threadIdx.x;
    const int lane = tid & 63;
    const int w    = tid >> 6;
    const int quad = lane >> 4;
    const int ln   = lane & 15;
    const int wm   = (w >> 1) * 64;
    const int wn   = (w & 1) * 64;
    const int lrow = lane >> 3;          // 0..7
    const int lcol = (lane & 7) * 8;     // u16 col

    f32x4 acc[4][4] = {};

    for (int k0 = 0; k0 < 256; k0 += 64) {
        __syncthreads();
        #pragma unroll
        for (int qq = 0; qq < 4; ++qq) {
            const int r = w * 32 + qq * 8;
            gld16(A + (size_t)(m0 + r + lrow) * 256 + k0 + lcol, &At[r * 64]);
            gld16(W + (size_t)(n0 + r + lrow) * 256 + k0 + lcol, &Wt[r * 64]);
        }
        __syncthreads();

        #pragma unroll
        for (int kk = 0; kk < 2; ++kk) {       // k ascending
            const int kc = kk * 32 + quad * 8;
            bf16x8 af[4], bfr[4];
            #pragma unroll
            for (int i = 0; i < 4; ++i)
                af[i] = __builtin_bit_cast(bf16x8, *(const uint4*)&At[(wm + i * 16 + ln) * 64 + kc]);
            #pragma unroll
            for (int j = 0; j < 4; ++j)
                bfr[j] = __builtin_bit_cast(bf16x8, *(const uint4*)&Wt[(wn + j * 16 + ln) * 64 + kc]);
            #pragma unroll
            for (int i = 0; i < 4; ++i)
                #pragma unroll
                for (int j = 0; j < 4; ++j)
                    acc[i][j] = __builtin_amdgcn_mfma_f32_16x16x32_bf16(af[i], bfr[j], acc[i][j], 0, 0, 0);
        }
    }

    const int act = (t == 3);
    #pragma unroll
    for (int i = 0; i < 4; ++i) {
        #pragma unroll
        for (int j = 0; j < 4; ++j) {
            #pragma unroll
            for (int rr = 0; rr < 4; ++rr) {
                const int row = m0 + wm + i * 16 + quad * 4 + rr;  // C/D row=quad*4+reg
                const int col = n0 + wn + j * 16 + ln;             //     col=lane&15
                float v = acc[i][j][rr];
                if (act) { v += bg[col]; v = 1.0f / (1.0f + __expf(-v)); }
                O[hm(row, col)] = f2bf(v);
            }
        }
    }
}

// -------------------------------------------------------------------------
// gemm_out: out = O @ Wo^T + bo (f32 out). O is head-major (aliases Qh).
// BM=64 -> 1024 blocks. Swizzle: m fastest -> n-siblings 512 apart.
// -------------------------------------------------------------------------
__global__ __launch_bounds__(256) void gemm_out(
    const u16* __restrict__ Oh, const u16* __restrict__ Wob,
    const float* __restrict__ bo, float* __restrict__ out)
{
    __shared__ u16 At[64 * 64];
    __shared__ u16 Wt[128 * 64];

    const int bid = blockIdx.x;
    const int m0  = (bid & 511) * 64;
    const int n0  = (bid >> 9) * 128;

    const int tid  = threadIdx.x;
    const int lane = tid & 63;
    const int w    = tid >> 6;
    const int quad = lane >> 4;
    const int ln   = lane & 15;
    const int wm   = (w >> 1) * 32;
    const int wn   = (w & 1) * 64;
    const int lrow = lane >> 3;
    const int lcol = (lane & 7) * 8;

    f32x4 acc[2][4] = {};

    for (int k0 = 0; k0 < 256; k0 += 64) {
        __syncthreads();
        #pragma unroll
        for (int qq = 0; qq < 2; ++qq) {
            const int r = w * 16 + qq * 8;
            // head-major A: per-lane address from (m, k)
            gld16(Oh + hm(m0 + r + lrow, k0 + lcol), &At[r * 64]);
        }
        #pragma unroll
        for (int qq = 0; qq < 4; ++qq) {
            const int r = w * 32 + qq * 8;
            gld16(Wob + (size_t)(n0 + r + lrow) * 256 + k0 + lcol, &Wt[r * 64]);
        }
        __syncthreads();

        #pragma unroll
        for (int kk = 0; kk < 2; ++kk) {
            const int kc = kk * 32 + quad * 8;
            bf16x8 af[2], bfr[4];
            #pragma unroll
            for (int i = 0; i < 2; ++i)
                af[i] = __builtin_bit_cast(bf16x8, *(const uint4*)&At[(wm + i * 16 + ln) * 64 + kc]);
            #pragma unroll
            for (int j = 0; j < 4; ++j)
                bfr[j] = __builtin_bit_cast(bf16x8, *(const uint4*)&Wt[(wn + j * 16 + ln) * 64 + kc]);
            #pragma unroll
            for (int i = 0; i < 2; ++i)
                #pragma unroll
                for (int j = 0; j < 4; ++j)
                    acc[i][j] = __builtin_amdgcn_mfma_f32_16x16x32_bf16(af[i], bfr[j], acc[i][j], 0, 0, 0);
        }
    }

    #pragma unroll
    for (int i = 0; i < 2; ++i) {
        #pragma unroll
        for (int j = 0; j < 4; ++j) {
            #pragma unroll
            for (int rr = 0; rr < 4; ++rr) {
                const int row = m0 + wm + i * 16 + quad * 4 + rr;
                const int col = n0 + wn + j * 16 + ln;
                out[(size_t)row * 256 + col] = acc[i][j][rr] + bo[col];
            }
        }
    }
}

// -------------------------------------------------------------------------
// attn: grid (1024 hs, 2). Each block stages V^T once and processes two qt
// tiles (qt = blockIdx.y*2 + iq). One 16-row m-tile per wave per qt.
// LDS = Vt 16.9K + Pl 9.7K + bmf 1K = 27.6KB -> 5 blocks/CU (was 3).
// Pl is wave-private: P-write + PV-MFMA chunked over k in 4 phases of 64,
// relying on in-wave LDS ordering (same pattern the unchunked version used).
// Bias add reads the prep-permuted f32 bppf via coalesced float4 loads;
// identical values + add order -> bit-identical output.
// O aliases Qh: wave reads only its own 16 Q rows before writing them.
// -------------------------------------------------------------------------
__global__ __launch_bounds__(256, 5) void attn_kernel(
    const u16* __restrict__ Qh, const u16* __restrict__ Kh, const u16* __restrict__ Vh,
    const u16* __restrict__ Gh, const float* __restrict__ bm, const float* __restrict__ bppf,
    u16* __restrict__ Oh)
{
    __shared__ u16   Vt[32][264];       // V transposed: Vt[dh][kp]
    __shared__ u16   Pl[4][16][76];     // per-wave P chunk (k-width 64)
    __shared__ float bmf[256];

    const int hs   = blockIdx.x;
    const int h    = hs & 7;
    const int s    = hs >> 3;
    const int tid  = threadIdx.x;
    const int lane = tid & 63;
    const int w    = tid >> 6;
    const int quad = lane >> 4;
    const int ln   = lane & 15;

    const size_t hsBase = ((size_t)(h * 128 + s) * 256) << 5;   // start of [h][s] slice

    {   // stage V^T (thread tid = key row; 64 B/thread, block-contiguous 16 KB)
        const uint4* vp = (const uint4*)(Vh + hsBase + (size_t)tid * 32);
        uint4 vv0 = vp[0], vv1 = vp[1], vv2 = vp[2], vv3 = vp[3];
        u16 tmp[32];
        *(uint4*)&tmp[0]  = vv0; *(uint4*)&tmp[8]  = vv1;
        *(uint4*)&tmp[16] = vv2; *(uint4*)&tmp[24] = vv3;
        #pragma unroll
        for (int dh = 0; dh < 32; ++dh) Vt[dh][tid] = tmp[dh];
        bmf[tid] = bm[s * 256 + tid];
    }
    __syncthreads();

    for (int iq = 0; iq < 2; ++iq) {
        const int qt = blockIdx.y * 2 + iq;
        const int q0 = qt * 64 + w * 16;

        bf16x8 aq = __builtin_bit_cast(bf16x8,
            *(const uint4*)(Qh + hsBase + (size_t)(q0 + ln) * 32 + quad * 8));

        f32x4 sc[16];
        #pragma unroll
        for (int nt = 0; nt < 16; ++nt) {
            bf16x8 bk = __builtin_bit_cast(bf16x8,
                *(const uint4*)(Kh + hsBase + (size_t)(nt * 16 + ln) * 32 + quad * 8));
            f32x4 z = {0.f, 0.f, 0.f, 0.f};
            sc[nt] = __builtin_amdgcn_mfma_f32_16x16x32_bf16(aq, bk, z, 0, 0, 0);
        }

        // bias add from permuted bppf: float4 per nt holds rr=0..3 for this
        // lane's q rows at kp = nt*16+ln. Same f32 values & add order as before.
        const float* bpt = bppf + ((size_t)(((h * 4 + qt) * 4 + w) * 16) * 64 + lane) * 4;
        float rmax[4] = {-1e30f, -1e30f, -1e30f, -1e30f};
        #pragma unroll
        for (int nt = 0; nt < 16; ++nt) {
            const f32x4 bv = *(const f32x4*)(bpt + (size_t)nt * 256);
            const float bmv = bmf[nt * 16 + ln];
            #pragma unroll
            for (int rr = 0; rr < 4; ++rr) {
                float v = sc[nt][rr] + bmv + bv[rr];
                sc[nt][rr] = v;
                rmax[rr] = fmaxf(rmax[rr], v);
            }
        }
        #pragma unroll
        for (int rr = 0; rr < 4; ++rr) {
            float m = rmax[rr];
            m = fmaxf(m, __shfl_xor(m, 1));
            m = fmaxf(m, __shfl_xor(m, 2));
            m = fmaxf(m, __shfl_xor(m, 4));
            m = fmaxf(m, __shfl_xor(m, 8));
            rmax[rr] = m;
        }
        float rsum[4] = {0.f, 0.f, 0.f, 0.f};
        #pragma unroll
        for (int nt = 0; nt < 16; ++nt)
            #pragma unroll
            for (int rr = 0; rr < 4; ++rr) {
                float p = __expf(sc[nt][rr] - rmax[rr]);
                sc[nt][rr] = p;
                rsum[rr] += p;
            }
        float rinv[4];
        #pragma unroll
        for (int rr = 0; rr < 4; ++rr) {
            float t = rsum[rr];
            t += __shfl_xor(t, 1);
            t += __shfl_xor(t, 2);
            t += __shfl_xor(t, 4);
            t += __shfl_xor(t, 8);
            rinv[rr] = 1.0f / t;
        }

        // chunked P-write + PV (k ascending, same accumulation order as before)
        f32x4 o0 = {0.f, 0.f, 0.f, 0.f}, o1 = {0.f, 0.f, 0.f, 0.f};
        #pragma unroll
        for (int c = 0; c < 4; ++c) {
            #pragma unroll
            for (int ntl = 0; ntl < 4; ++ntl) {
                const int nt = c * 4 + ntl;
                #pragma unroll
                for (int rr = 0; rr < 4; ++rr)
                    Pl[w][quad * 4 + rr][ntl * 16 + ln] = f2bf(sc[nt][rr] * rinv[rr]);
            }
            #pragma unroll
            for (int kcl = 0; kcl < 2; ++kcl) {
                bf16x8 pa = __builtin_bit_cast(bf16x8, *(const uint4*)&Pl[w][ln][kcl * 32 + quad * 8]);
                bf16x8 v0 = __builtin_bit_cast(bf16x8, *(const uint4*)&Vt[ln][c * 64 + kcl * 32 + quad * 8]);
                bf16x8 v1 = __builtin_bit_cast(bf16x8, *(const uint4*)&Vt[16 + ln][c * 64 + kcl * 32 + quad * 8]);
                o0 = __builtin_amdgcn_mfma_f32_16x16x32_bf16(pa, v0, o0, 0, 0, 0);
                o1 = __builtin_amdgcn_mfma_f32_16x16x32_bf16(pa, v1, o1, 0, 0, 0);
            }
        }

        #pragma unroll
        for (int rr = 0; rr < 4; ++rr) {
            const int q = q0 + quad * 4 + rr;
            const size_t base = hsBase + (size_t)q * 32;
            float g0 = bf2f(Gh[base + ln]);
            float g1 = bf2f(Gh[base + 16 + ln]);
            Oh[base + ln]      = f2bf(o0[rr] * g0);
            Oh[base + 16 + ln] = f2bf(o1[rr] * g1);
        }
    }
}

// -------------------------------------------------------------------------
extern "C" void kernel_launch(void* const* d_in, const int* in_sizes, int n_in,
                              void* d_out, int out_size, void* d_ws, size_t ws_size,
                              hipStream_t stream)
{
    const float* qx  = (const float*)d_in[0];
    const float* kvx = (const float*)d_in[1];
    const float* bm  = (const float*)d_in[2];
    const float* bp  = (const float*)d_in[3];
    const float* Wq  = (const float*)d_in[4];
    const float* Wk  = (const float*)d_in[5];
    const float* Wv  = (const float*)d_in[6];
    const float* Wg  = (const float*)d_in[7];
    const float* bg  = (const float*)d_in[8];
    const float* Wo  = (const float*)d_in[9];
    const float* bo  = (const float*)d_in[10];
    float* out = (float*)d_out;

    // ws: Qh(=Oh), Kh, Vh, Gh (bf16, 16.78 MB each, head-major) + weights
    //     + permuted f32 bias_pair (2 MB). Total ~69.9 MB.
    const size_t NEL = (size_t)32768 * 256;
    u16* Qh = (u16*)d_ws;            // also Oh
    u16* Kh = Qh + NEL;
    u16* Vh = Kh + NEL;
    u16* Gh = Vh + NEL;
    u16* Wball = Gh + NEL;           // 5 * 65536 u16
    float* bppf = (float*)(Wball + 5 * 65536);   // 524288 f32

    // d_out doubles as bf16 scratch for qx/kvx; overwritten by gemm_out.
    u16* Xq  = (u16*)d_out;
    u16* Xkv = Xq + NEL;

    prep<<<dim3(8608), dim3(256), 0, stream>>>(qx, kvx, Wq, Wk, Wv, Wg, Wo, bp,
                                               Xq, Xkv, Wball, bppf);

    proj_all<<<dim3(2048), dim3(256), 0, stream>>>(Xq, Xkv, Wball, bg, Qh, Kh, Vh, Gh);

    attn_kernel<<<dim3(1024, 2), dim3(256), 0, stream>>>(Qh, Kh, Vh, Gh, bm, bppf, Qh /*Oh*/);

    gemm_out<<<dim3(1024), dim3(256), 0, stream>>>(Qh /*Oh*/, Wball + 4 * 65536, bo, out);
}

// Round 2
// 270.907 us; speedup vs baseline: 1.1070x; 1.1070x over previous
//
#include <hip/hip_runtime.h>

// Shapes: B=1, S=128, Q=256, C=256, H=8, DH=32, TOT=256. Inputs/out f32.
// Numerics bit-identical to R2-R8 (absmax 0.01953125 vs thr 0.019609).
// R9: fix R8's regression. launch_bounds(256,5) capped VGPR at 48 -> sc[16]
// spilled to scratch (WRITE_SIZE 16->221 MB, FETCH 76->250 MB, dur 56->128us).
// Relax to (256,4): VGPR cap 128 fits the ~100-reg body, LDS 27.6KB allows
// 4 blocks/CU -> 50% occupancy cap (baseline was LDS-capped at 37.5%).
// Keeps R8's wins: wave-private Pl chunked over k (LDS 52.2->27.6 KB),
// prep-permuted f32 bias_pair (coalesced float4 bias add), qt pairing.

typedef unsigned short u16;
typedef unsigned int   u32;
typedef float  f32x4  __attribute__((ext_vector_type(4)));
typedef __bf16 bf16x8 __attribute__((ext_vector_type(8)));

__device__ __forceinline__ float bf2f(u16 u) {
    union { u32 i; float f; } v; v.i = ((u32)u) << 16; return v.f;
}
__device__ __forceinline__ u16 f2bf(float f) {      // hw RNE cvt
    __bf16 h = (__bf16)f; return __builtin_bit_cast(u16, h);
}

// async global->LDS, 16B/lane; lds dest wave-uniform base (HW adds lane*16)
__device__ __forceinline__ void gld16(const u16* g, u16* l) {
    __builtin_amdgcn_global_load_lds(
        (const __attribute__((address_space(1))) u32*)g,
        (__attribute__((address_space(3))) u32*)l, 16, 0, 0);
}

// head-major offset for logical (row = s*256+q, col = h*32+dh)
__device__ __forceinline__ size_t hm(int row, int col) {
    const int s = row >> 8, q = row & 255, h = col >> 5, dh = col & 31;
    return ((size_t)((h * 128 + s) * 256 + q) << 5) + dh;
}

// -------------------------------------------------------------------------
// prep: f32 -> bf16 for qx, kvx (into d_out scratch) and the 5 weight mats,
// plus f32 permute of bias_pair into bppf[(h,qt,w)][nt][lane][rr].
// -------------------------------------------------------------------------
__device__ __forceinline__ void cvt8(const float4* src, u16* dst) {
    float4 a = src[0], b = src[1];
    u16 r[8];
    r[0] = f2bf(a.x); r[1] = f2bf(a.y); r[2] = f2bf(a.z); r[3] = f2bf(a.w);
    r[4] = f2bf(b.x); r[5] = f2bf(b.y); r[6] = f2bf(b.z); r[7] = f2bf(b.w);
    *(uint4*)dst = *(uint4*)r;
}

__global__ __launch_bounds__(256) void prep(
    const float* __restrict__ qx, const float* __restrict__ kvx,
    const float* __restrict__ Wq, const float* __restrict__ Wk,
    const float* __restrict__ Wv, const float* __restrict__ Wg,
    const float* __restrict__ Wo, const float* __restrict__ bp,
    u16* __restrict__ Xq, u16* __restrict__ Xkv, u16* __restrict__ Wball,
    float* __restrict__ bppf)
{
    const int b = blockIdx.x, t = threadIdx.x;
    if (b < 4096) {
        const int e = (b * 256 + t) * 8;
        cvt8((const float4*)(qx + e), Xq + e);
    } else if (b < 8192) {
        const int e = ((b - 4096) * 256 + t) * 8;
        cvt8((const float4*)(kvx + e), Xkv + e);
    } else if (b < 8352) {
        const int b2  = b - 8192;            // 0..159: 32 blocks per matrix
        const int mat = b2 >> 5;
        const float* W = (mat == 0) ? Wq : (mat == 1) ? Wk : (mat == 2) ? Wv
                       : (mat == 3) ? Wg : Wo;
        const int off = (b2 & 31) * 2048 + t * 8;
        cvt8((const float4*)(W + off), Wball + mat * 65536 + off);
    } else {
        // bias_pair permute: unit u = ((h*4+qt)*4+w)*16*64 + nt*64 + lane,
        // holds bp rows q0..q0+3 (rr in float4 lanes) at col kp.
        const int b3 = b - 8352;             // 0..255
        const int u0 = (b3 * 256 + t) * 2;
        #pragma unroll
        for (int k2 = 0; k2 < 2; ++k2) {
            const int u  = u0 + k2;
            const int l  = u & 63;
            const int nt = (u >> 6) & 15;
            const int tt = u >> 10;          // (h*4+qt)*4+w, 0..127
            const int ww = tt & 3, qqt = (tt >> 2) & 3, hh = tt >> 4;
            const int qb = qqt * 64 + ww * 16 + (l >> 4) * 4;
            const int kp = nt * 16 + (l & 15);
            const float* src = bp + (size_t)(hh * 256 + qb) * 256 + kp;
            float4 v;
            v.x = src[0]; v.y = src[256]; v.z = src[512]; v.w = src[768];
            *(float4*)(bppf + (size_t)u * 4) = v;
        }
    }
}

// -------------------------------------------------------------------------
// proj_all: fused Q/K/V/G projections, m97 structure. 2048 blocks.
// Block tile 128x128, BK=64, 4 waves 2x2, wave 64x64 (4x4 frags).
// Swizzle: mb = bid&255 -> 8 A-sharing siblings 256 apart == same XCD.
// Output written HEAD-MAJOR via hm().
// -------------------------------------------------------------------------
__global__ __launch_bounds__(256) void proj_all(
    const u16* __restrict__ Xq, const u16* __restrict__ Xkv,
    const u16* __restrict__ Wball, const float* __restrict__ bg,
    u16* __restrict__ Qh, u16* __restrict__ Kh, u16* __restrict__ Vh, u16* __restrict__ Gh)
{
    __shared__ u16 At[128 * 64];     // unpadded: required by global_load_lds
    __shared__ u16 Wt[128 * 64];

    const int bid = blockIdx.x;
    const int mb  = bid & 255;
    const int nb  = bid >> 8;        // 0..7
    const int t   = nb >> 1;         // 0=Q 1=K 2=V 3=G
    const int n0  = (nb & 1) * 128;
    const int m0  = mb * 128;
    const u16* A = (t == 0 || t == 3) ? Xq : Xkv;
    const u16* W = Wball + t * 65536;
    u16*       O = (t == 0) ? Qh : (t == 1) ? Kh : (t == 2) ? Vh : Gh;

    const int tid  = threadIdx.x;
    const int lane = tid & 63;
    const int w    = tid >> 6;
    const int quad = lane >> 4;
    const int ln   = lane & 15;
    const int wm   = (w >> 1) * 64;
    const int wn   = (w & 1) * 64;
    const int lrow = lane >> 3;          // 0..7
    const int lcol = (lane & 7) * 8;     // u16 col

    f32x4 acc[4][4] = {};

    for (int k0 = 0; k0 < 256; k0 += 64) {
        __syncthreads();
        #pragma unroll
        for (int qq = 0; qq < 4; ++qq) {
            const int r = w * 32 + qq * 8;
            gld16(A + (size_t)(m0 + r + lrow) * 256 + k0 + lcol, &At[r * 64]);
            gld16(W + (size_t)(n0 + r + lrow) * 256 + k0 + lcol, &Wt[r * 64]);
        }
        __syncthreads();

        #pragma unroll
        for (int kk = 0; kk < 2; ++kk) {       // k ascending
            const int kc = kk * 32 + quad * 8;
            bf16x8 af[4], bfr[4];
            #pragma unroll
            for (int i = 0; i < 4; ++i)
                af[i] = __builtin_bit_cast(bf16x8, *(const uint4*)&At[(wm + i * 16 + ln) * 64 + kc]);
            #pragma unroll
            for (int j = 0; j < 4; ++j)
                bfr[j] = __builtin_bit_cast(bf16x8, *(const uint4*)&Wt[(wn + j * 16 + ln) * 64 + kc]);
            #pragma unroll
            for (int i = 0; i < 4; ++i)
                #pragma unroll
                for (int j = 0; j < 4; ++j)
                    acc[i][j] = __builtin_amdgcn_mfma_f32_16x16x32_bf16(af[i], bfr[j], acc[i][j], 0, 0, 0);
        }
    }

    const int act = (t == 3);
    #pragma unroll
    for (int i = 0; i < 4; ++i) {
        #pragma unroll
        for (int j = 0; j < 4; ++j) {
            #pragma unroll
            for (int rr = 0; rr < 4; ++rr) {
                const int row = m0 + wm + i * 16 + quad * 4 + rr;  // C/D row=quad*4+reg
                const int col = n0 + wn + j * 16 + ln;             //     col=lane&15
                float v = acc[i][j][rr];
                if (act) { v += bg[col]; v = 1.0f / (1.0f + __expf(-v)); }
                O[hm(row, col)] = f2bf(v);
            }
        }
    }
}

// -------------------------------------------------------------------------
// gemm_out: out = O @ Wo^T + bo (f32 out). O is head-major (aliases Qh).
// BM=64 -> 1024 blocks. Swizzle: m fastest -> n-siblings 512 apart.
// -------------------------------------------------------------------------
__global__ __launch_bounds__(256) void gemm_out(
    const u16* __restrict__ Oh, const u16* __restrict__ Wob,
    const float* __restrict__ bo, float* __restrict__ out)
{
    __shared__ u16 At[64 * 64];
    __shared__ u16 Wt[128 * 64];

    const int bid = blockIdx.x;
    const int m0  = (bid & 511) * 64;
    const int n0  = (bid >> 9) * 128;

    const int tid  = threadIdx.x;
    const int lane = tid & 63;
    const int w    = tid >> 6;
    const int quad = lane >> 4;
    const int ln   = lane & 15;
    const int wm   = (w >> 1) * 32;
    const int wn   = (w & 1) * 64;
    const int lrow = lane >> 3;
    const int lcol = (lane & 7) * 8;

    f32x4 acc[2][4] = {};

    for (int k0 = 0; k0 < 256; k0 += 64) {
        __syncthreads();
        #pragma unroll
        for (int qq = 0; qq < 2; ++qq) {
            const int r = w * 16 + qq * 8;
            // head-major A: per-lane address from (m, k)
            gld16(Oh + hm(m0 + r + lrow, k0 + lcol), &At[r * 64]);
        }
        #pragma unroll
        for (int qq = 0; qq < 4; ++qq) {
            const int r = w * 32 + qq * 8;
            gld16(Wob + (size_t)(n0 + r + lrow) * 256 + k0 + lcol, &Wt[r * 64]);
        }
        __syncthreads();

        #pragma unroll
        for (int kk = 0; kk < 2; ++kk) {
            const int kc = kk * 32 + quad * 8;
            bf16x8 af[2], bfr[4];
            #pragma unroll
            for (int i = 0; i < 2; ++i)
                af[i] = __builtin_bit_cast(bf16x8, *(const uint4*)&At[(wm + i * 16 + ln) * 64 + kc]);
            #pragma unroll
            for (int j = 0; j < 4; ++j)
                bfr[j] = __builtin_bit_cast(bf16x8, *(const uint4*)&Wt[(wn + j * 16 + ln) * 64 + kc]);
            #pragma unroll
            for (int i = 0; i < 2; ++i)
                #pragma unroll
                for (int j = 0; j < 4; ++j)
                    acc[i][j] = __builtin_amdgcn_mfma_f32_16x16x32_bf16(af[i], bfr[j], acc[i][j], 0, 0, 0);
        }
    }

    #pragma unroll
    for (int i = 0; i < 2; ++i) {
        #pragma unroll
        for (int j = 0; j < 4; ++j) {
            #pragma unroll
            for (int rr = 0; rr < 4; ++rr) {
                const int row = m0 + wm + i * 16 + quad * 4 + rr;
                const int col = n0 + wn + j * 16 + ln;
                out[(size_t)row * 256 + col] = acc[i][j][rr] + bo[col];
            }
        }
    }
}

// -------------------------------------------------------------------------
// attn: grid (1024 hs, 2). Each block stages V^T once and processes two qt
// tiles (qt = blockIdx.y*2 + iq). One 16-row m-tile per wave per qt.
// LDS = Vt 16.9K + Pl 9.7K + bmf 1K = 27.6KB -> LDS cap 5 blocks/CU.
// launch_bounds(256,4): VGPR cap 128 (body needs ~100; (256,5)'s cap of 102
// forced sc[16] spill -> 221MB scratch writes, R8 regression).
// Pl is wave-private: P-write + PV-MFMA chunked over k in 4 phases of 64,
// relying on in-wave LDS ordering (same pattern the unchunked version used).
// Bias add reads the prep-permuted f32 bppf via coalesced float4 loads;
// identical values + add order -> bit-identical output.
// O aliases Qh: wave reads only its own 16 Q rows before writing them.
// -------------------------------------------------------------------------
__global__ __launch_bounds__(256, 4) void attn_kernel(
    const u16* __restrict__ Qh, const u16* __restrict__ Kh, const u16* __restrict__ Vh,
    const u16* __restrict__ Gh, const float* __restrict__ bm, const float* __restrict__ bppf,
    u16* __restrict__ Oh)
{
    __shared__ u16   Vt[32][264];       // V transposed: Vt[dh][kp]
    __shared__ u16   Pl[4][16][76];     // per-wave P chunk (k-width 64)
    __shared__ float bmf[256];

    const int hs   = blockIdx.x;
    const int h    = hs & 7;
    const int s    = hs >> 3;
    const int tid  = threadIdx.x;
    const int lane = tid & 63;
    const int w    = tid >> 6;
    const int quad = lane >> 4;
    const int ln   = lane & 15;

    const size_t hsBase = ((size_t)(h * 128 + s) * 256) << 5;   // start of [h][s] slice

    {   // stage V^T (thread tid = key row; 64 B/thread, block-contiguous 16 KB)
        const uint4* vp = (const uint4*)(Vh + hsBase + (size_t)tid * 32);
        uint4 vv0 = vp[0], vv1 = vp[1], vv2 = vp[2], vv3 = vp[3];
        u16 tmp[32];
        *(uint4*)&tmp[0]  = vv0; *(uint4*)&tmp[8]  = vv1;
        *(uint4*)&tmp[16] = vv2; *(uint4*)&tmp[24] = vv3;
        #pragma unroll
        for (int dh = 0; dh < 32; ++dh) Vt[dh][tid] = tmp[dh];
        bmf[tid] = bm[s * 256 + tid];
    }
    __syncthreads();

    for (int iq = 0; iq < 2; ++iq) {
        const int qt = blockIdx.y * 2 + iq;
        const int q0 = qt * 64 + w * 16;

        bf16x8 aq = __builtin_bit_cast(bf16x8,
            *(const uint4*)(Qh + hsBase + (size_t)(q0 + ln) * 32 + quad * 8));

        f32x4 sc[16];
        #pragma unroll
        for (int nt = 0; nt < 16; ++nt) {
            bf16x8 bk = __builtin_bit_cast(bf16x8,
                *(const uint4*)(Kh + hsBase + (size_t)(nt * 16 + ln) * 32 + quad * 8));
            f32x4 z = {0.f, 0.f, 0.f, 0.f};
            sc[nt] = __builtin_amdgcn_mfma_f32_16x16x32_bf16(aq, bk, z, 0, 0, 0);
        }

        // bias add from permuted bppf: float4 per nt holds rr=0..3 for this
        // lane's q rows at kp = nt*16+ln. Same f32 values & add order as before.
        const float* bpt = bppf + ((size_t)(((h * 4 + qt) * 4 + w) * 16) * 64 + lane) * 4;
        float rmax[4] = {-1e30f, -1e30f, -1e30f, -1e30f};
        #pragma unroll
        for (int nt = 0; nt < 16; ++nt) {
            const f32x4 bv = *(const f32x4*)(bpt + (size_t)nt * 256);
            const float bmv = bmf[nt * 16 + ln];
            #pragma unroll
            for (int rr = 0; rr < 4; ++rr) {
                float v = sc[nt][rr] + bmv + bv[rr];
                sc[nt][rr] = v;
                rmax[rr] = fmaxf(rmax[rr], v);
            }
        }
        #pragma unroll
        for (int rr = 0; rr < 4; ++rr) {
            float m = rmax[rr];
            m = fmaxf(m, __shfl_xor(m, 1));
            m = fmaxf(m, __shfl_xor(m, 2));
            m = fmaxf(m, __shfl_xor(m, 4));
            m = fmaxf(m, __shfl_xor(m, 8));
            rmax[rr] = m;
        }
        float rsum[4] = {0.f, 0.f, 0.f, 0.f};
        #pragma unroll
        for (int nt = 0; nt < 16; ++nt)
            #pragma unroll
            for (int rr = 0; rr < 4; ++rr) {
                float p = __expf(sc[nt][rr] - rmax[rr]);
                sc[nt][rr] = p;
                rsum[rr] += p;
            }
        float rinv[4];
        #pragma unroll
        for (int rr = 0; rr < 4; ++rr) {
            float t = rsum[rr];
            t += __shfl_xor(t, 1);
            t += __shfl_xor(t, 2);
            t += __shfl_xor(t, 4);
            t += __shfl_xor(t, 8);
            rinv[rr] = 1.0f / t;
        }

        // chunked P-write + PV (k ascending, same accumulation order as before)
        f32x4 o0 = {0.f, 0.f, 0.f, 0.f}, o1 = {0.f, 0.f, 0.f, 0.f};
        #pragma unroll
        for (int c = 0; c < 4; ++c) {
            #pragma unroll
            for (int ntl = 0; ntl < 4; ++ntl) {
                const int nt = c * 4 + ntl;
                #pragma unroll
                for (int rr = 0; rr < 4; ++rr)
                    Pl[w][quad * 4 + rr][ntl * 16 + ln] = f2bf(sc[nt][rr] * rinv[rr]);
            }
            #pragma unroll
            for (int kcl = 0; kcl < 2; ++kcl) {
                bf16x8 pa = __builtin_bit_cast(bf16x8, *(const uint4*)&Pl[w][ln][kcl * 32 + quad * 8]);
                bf16x8 v0 = __builtin_bit_cast(bf16x8, *(const uint4*)&Vt[ln][c * 64 + kcl * 32 + quad * 8]);
                bf16x8 v1 = __builtin_bit_cast(bf16x8, *(const uint4*)&Vt[16 + ln][c * 64 + kcl * 32 + quad * 8]);
                o0 = __builtin_amdgcn_mfma_f32_16x16x32_bf16(pa, v0, o0, 0, 0, 0);
                o1 = __builtin_amdgcn_mfma_f32_16x16x32_bf16(pa, v1, o1, 0, 0, 0);
            }
        }

        #pragma unroll
        for (int rr = 0; rr < 4; ++rr) {
            const int q = q0 + quad * 4 + rr;
            const size_t base = hsBase + (size_t)q * 32;
            float g0 = bf2f(Gh[base + ln]);
            float g1 = bf2f(Gh[base + 16 + ln]);
            Oh[base + ln]      = f2bf(o0[rr] * g0);
            Oh[base + 16 + ln] = f2bf(o1[rr] * g1);
        }
    }
}

// -------------------------------------------------------------------------
extern "C" void kernel_launch(void* const* d_in, const int* in_sizes, int n_in,
                              void* d_out, int out_size, void* d_ws, size_t ws_size,
                              hipStream_t stream)
{
    const float* qx  = (const float*)d_in[0];
    const float* kvx = (const float*)d_in[1];
    const float* bm  = (const float*)d_in[2];
    const float* bp  = (const float*)d_in[3];
    const float* Wq  = (const float*)d_in[4];
    const float* Wk  = (const float*)d_in[5];
    const float* Wv  = (const float*)d_in[6];
    const float* Wg  = (const float*)d_in[7];
    const float* bg  = (const float*)d_in[8];
    const float* Wo  = (const float*)d_in[9];
    const float* bo  = (const float*)d_in[10];
    float* out = (float*)d_out;

    // ws: Qh(=Oh), Kh, Vh, Gh (bf16, 16.78 MB each, head-major) + weights
    //     + permuted f32 bias_pair (2 MB). Total ~69.9 MB.
    const size_t NEL = (size_t)32768 * 256;
    u16* Qh = (u16*)d_ws;            // also Oh
    u16* Kh = Qh + NEL;
    u16* Vh = Kh + NEL;
    u16* Gh = Vh + NEL;
    u16* Wball = Gh + NEL;           // 5 * 65536 u16
    float* bppf = (float*)(Wball + 5 * 65536);   // 524288 f32

    // d_out doubles as bf16 scratch for qx/kvx; overwritten by gemm_out.
    u16* Xq  = (u16*)d_out;
    u16* Xkv = Xq + NEL;

    prep<<<dim3(8608), dim3(256), 0, stream>>>(qx, kvx, Wq, Wk, Wv, Wg, Wo, bp,
                                               Xq, Xkv, Wball, bppf);

    proj_all<<<dim3(2048), dim3(256), 0, stream>>>(Xq, Xkv, Wball, bg, Qh, Kh, Vh, Gh);

    attn_kernel<<<dim3(1024, 2), dim3(256), 0, stream>>>(Qh, Kh, Vh, Gh, bm, bppf, Qh /*Oh*/);

    gemm_out<<<dim3(1024), dim3(256), 0, stream>>>(Qh /*Oh*/, Wball + 4 * 65536, bo, out);
}

// Round 4
// 226.246 us; speedup vs baseline: 1.3256x; 1.1974x over previous
//
#include <hip/hip_runtime.h>

// Shapes: B=1, S=128, Q=256, C=256, H=8, DH=32, TOT=256. Inputs/out f32.
// Numerics bit-identical to R2-R9 (absmax 0.01953125 vs thr 0.019609).
// R11 == R10 resubmit (bench infra failed; kernel never ran).
// R10: fix the spill for real. Empirically hipcc budgets ARCH-VGPRs as
// 256/min_waves: (256,5)->48 regs, (256,4)->64 regs -- both below the ~76+
// the body needs (sc[16]=64 regs), so both spilled (WRITE_SIZE 221/147 MB).
// (256,2) -> cap 128: fits the ~100-reg body, no spill; 76-128 regs still
// gives 16 waves/CU = 4 blocks/CU = 50% occupancy (LDS 27.6KB allows 5).
// Keeps R8's wins: wave-private Pl chunked over k (LDS 52.2->27.6 KB),
// prep-permuted f32 bias_pair (coalesced float4 bias add), qt pairing.

typedef unsigned short u16;
typedef unsigned int   u32;
typedef float  f32x4  __attribute__((ext_vector_type(4)));
typedef __bf16 bf16x8 __attribute__((ext_vector_type(8)));

__device__ __forceinline__ float bf2f(u16 u) {
    union { u32 i; float f; } v; v.i = ((u32)u) << 16; return v.f;
}
__device__ __forceinline__ u16 f2bf(float f) {      // hw RNE cvt
    __bf16 h = (__bf16)f; return __builtin_bit_cast(u16, h);
}

// async global->LDS, 16B/lane; lds dest wave-uniform base (HW adds lane*16)
__device__ __forceinline__ void gld16(const u16* g, u16* l) {
    __builtin_amdgcn_global_load_lds(
        (const __attribute__((address_space(1))) u32*)g,
        (__attribute__((address_space(3))) u32*)l, 16, 0, 0);
}

// head-major offset for logical (row = s*256+q, col = h*32+dh)
__device__ __forceinline__ size_t hm(int row, int col) {
    const int s = row >> 8, q = row & 255, h = col >> 5, dh = col & 31;
    return ((size_t)((h * 128 + s) * 256 + q) << 5) + dh;
}

// -------------------------------------------------------------------------
// prep: f32 -> bf16 for qx, kvx (into d_out scratch) and the 5 weight mats,
// plus f32 permute of bias_pair into bppf[(h,qt,w)][nt][lane][rr].
// -------------------------------------------------------------------------
__device__ __forceinline__ void cvt8(const float4* src, u16* dst) {
    float4 a = src[0], b = src[1];
    u16 r[8];
    r[0] = f2bf(a.x); r[1] = f2bf(a.y); r[2] = f2bf(a.z); r[3] = f2bf(a.w);
    r[4] = f2bf(b.x); r[5] = f2bf(b.y); r[6] = f2bf(b.z); r[7] = f2bf(b.w);
    *(uint4*)dst = *(uint4*)r;
}

__global__ __launch_bounds__(256) void prep(
    const float* __restrict__ qx, const float* __restrict__ kvx,
    const float* __restrict__ Wq, const float* __restrict__ Wk,
    const float* __restrict__ Wv, const float* __restrict__ Wg,
    const float* __restrict__ Wo, const float* __restrict__ bp,
    u16* __restrict__ Xq, u16* __restrict__ Xkv, u16* __restrict__ Wball,
    float* __restrict__ bppf)
{
    const int b = blockIdx.x, t = threadIdx.x;
    if (b < 4096) {
        const int e = (b * 256 + t) * 8;
        cvt8((const float4*)(qx + e), Xq + e);
    } else if (b < 8192) {
        const int e = ((b - 4096) * 256 + t) * 8;
        cvt8((const float4*)(kvx + e), Xkv + e);
    } else if (b < 8352) {
        const int b2  = b - 8192;            // 0..159: 32 blocks per matrix
        const int mat = b2 >> 5;
        const float* W = (mat == 0) ? Wq : (mat == 1) ? Wk : (mat == 2) ? Wv
                       : (mat == 3) ? Wg : Wo;
        const int off = (b2 & 31) * 2048 + t * 8;
        cvt8((const float4*)(W + off), Wball + mat * 65536 + off);
    } else {
        // bias_pair permute: unit u = ((h*4+qt)*4+w)*16*64 + nt*64 + lane,
        // holds bp rows q0..q0+3 (rr in float4 lanes) at col kp.
        const int b3 = b - 8352;             // 0..255
        const int u0 = (b3 * 256 + t) * 2;
        #pragma unroll
        for (int k2 = 0; k2 < 2; ++k2) {
            const int u  = u0 + k2;
            const int l  = u & 63;
            const int nt = (u >> 6) & 15;
            const int tt = u >> 10;          // (h*4+qt)*4+w, 0..127
            const int ww = tt & 3, qqt = (tt >> 2) & 3, hh = tt >> 4;
            const int qb = qqt * 64 + ww * 16 + (l >> 4) * 4;
            const int kp = nt * 16 + (l & 15);
            const float* src = bp + (size_t)(hh * 256 + qb) * 256 + kp;
            float4 v;
            v.x = src[0]; v.y = src[256]; v.z = src[512]; v.w = src[768];
            *(float4*)(bppf + (size_t)u * 4) = v;
        }
    }
}

// -------------------------------------------------------------------------
// proj_all: fused Q/K/V/G projections, m97 structure. 2048 blocks.
// Block tile 128x128, BK=64, 4 waves 2x2, wave 64x64 (4x4 frags).
// Swizzle: mb = bid&255 -> 8 A-sharing siblings 256 apart == same XCD.
// Output written HEAD-MAJOR via hm().
// -------------------------------------------------------------------------
__global__ __launch_bounds__(256) void proj_all(
    const u16* __restrict__ Xq, const u16* __restrict__ Xkv,
    const u16* __restrict__ Wball, const float* __restrict__ bg,
    u16* __restrict__ Qh, u16* __restrict__ Kh, u16* __restrict__ Vh, u16* __restrict__ Gh)
{
    __shared__ u16 At[128 * 64];     // unpadded: required by global_load_lds
    __shared__ u16 Wt[128 * 64];

    const int bid = blockIdx.x;
    const int mb  = bid & 255;
    const int nb  = bid >> 8;        // 0..7
    const int t   = nb >> 1;         // 0=Q 1=K 2=V 3=G
    const int n0  = (nb & 1) * 128;
    const int m0  = mb * 128;
    const u16* A = (t == 0 || t == 3) ? Xq : Xkv;
    const u16* W = Wball + t * 65536;
    u16*       O = (t == 0) ? Qh : (t == 1) ? Kh : (t == 2) ? Vh : Gh;

    const int tid  = threadIdx.x;
    const int lane = tid & 63;
    const int w    = tid >> 6;
    const int quad = lane >> 4;
    const int ln   = lane & 15;
    const int wm   = (w >> 1) * 64;
    const int wn   = (w & 1) * 64;
    const int lrow = lane >> 3;          // 0..7
    const int lcol = (lane & 7) * 8;     // u16 col

    f32x4 acc[4][4] = {};

    for (int k0 = 0; k0 < 256; k0 += 64) {
        __syncthreads();
        #pragma unroll
        for (int qq = 0; qq < 4; ++qq) {
            const int r = w * 32 + qq * 8;
            gld16(A + (size_t)(m0 + r + lrow) * 256 + k0 + lcol, &At[r * 64]);
            gld16(W + (size_t)(n0 + r + lrow) * 256 + k0 + lcol, &Wt[r * 64]);
        }
        __syncthreads();

        #pragma unroll
        for (int kk = 0; kk < 2; ++kk) {       // k ascending
            const int kc = kk * 32 + quad * 8;
            bf16x8 af[4], bfr[4];
            #pragma unroll
            for (int i = 0; i < 4; ++i)
                af[i] = __builtin_bit_cast(bf16x8, *(const uint4*)&At[(wm + i * 16 + ln) * 64 + kc]);
            #pragma unroll
            for (int j = 0; j < 4; ++j)
                bfr[j] = __builtin_bit_cast(bf16x8, *(const uint4*)&Wt[(wn + j * 16 + ln) * 64 + kc]);
            #pragma unroll
            for (int i = 0; i < 4; ++i)
                #pragma unroll
                for (int j = 0; j < 4; ++j)
                    acc[i][j] = __builtin_amdgcn_mfma_f32_16x16x32_bf16(af[i], bfr[j], acc[i][j], 0, 0, 0);
        }
    }

    const int act = (t == 3);
    #pragma unroll
    for (int i = 0; i < 4; ++i) {
        #pragma unroll
        for (int j = 0; j < 4; ++j) {
            #pragma unroll
            for (int rr = 0; rr < 4; ++rr) {
                const int row = m0 + wm + i * 16 + quad * 4 + rr;  // C/D row=quad*4+reg
                const int col = n0 + wn + j * 16 + ln;             //     col=lane&15
                float v = acc[i][j][rr];
                if (act) { v += bg[col]; v = 1.0f / (1.0f + __expf(-v)); }
                O[hm(row, col)] = f2bf(v);
            }
        }
    }
}

// -------------------------------------------------------------------------
// gemm_out: out = O @ Wo^T + bo (f32 out). O is head-major (aliases Qh).
// BM=64 -> 1024 blocks. Swizzle: m fastest -> n-siblings 512 apart.
// -------------------------------------------------------------------------
__global__ __launch_bounds__(256) void gemm_out(
    const u16* __restrict__ Oh, const u16* __restrict__ Wob,
    const float* __restrict__ bo, float* __restrict__ out)
{
    __shared__ u16 At[64 * 64];
    __shared__ u16 Wt[128 * 64];

    const int bid = blockIdx.x;
    const int m0  = (bid & 511) * 64;
    const int n0  = (bid >> 9) * 128;

    const int tid  = threadIdx.x;
    const int lane = tid & 63;
    const int w    = tid >> 6;
    const int quad = lane >> 4;
    const int ln   = lane & 15;
    const int wm   = (w >> 1) * 32;
    const int wn   = (w & 1) * 64;
    const int lrow = lane >> 3;
    const int lcol = (lane & 7) * 8;

    f32x4 acc[2][4] = {};

    for (int k0 = 0; k0 < 256; k0 += 64) {
        __syncthreads();
        #pragma unroll
        for (int qq = 0; qq < 2; ++qq) {
            const int r = w * 16 + qq * 8;
            // head-major A: per-lane address from (m, k)
            gld16(Oh + hm(m0 + r + lrow, k0 + lcol), &At[r * 64]);
        }
        #pragma unroll
        for (int qq = 0; qq < 4; ++qq) {
            const int r = w * 32 + qq * 8;
            gld16(Wob + (size_t)(n0 + r + lrow) * 256 + k0 + lcol, &Wt[r * 64]);
        }
        __syncthreads();

        #pragma unroll
        for (int kk = 0; kk < 2; ++kk) {
            const int kc = kk * 32 + quad * 8;
            bf16x8 af[2], bfr[4];
            #pragma unroll
            for (int i = 0; i < 2; ++i)
                af[i] = __builtin_bit_cast(bf16x8, *(const uint4*)&At[(wm + i * 16 + ln) * 64 + kc]);
            #pragma unroll
            for (int j = 0; j < 4; ++j)
                bfr[j] = __builtin_bit_cast(bf16x8, *(const uint4*)&Wt[(wn + j * 16 + ln) * 64 + kc]);
            #pragma unroll
            for (int i = 0; i < 2; ++i)
                #pragma unroll
                for (int j = 0; j < 4; ++j)
                    acc[i][j] = __builtin_amdgcn_mfma_f32_16x16x32_bf16(af[i], bfr[j], acc[i][j], 0, 0, 0);
        }
    }

    #pragma unroll
    for (int i = 0; i < 2; ++i) {
        #pragma unroll
        for (int j = 0; j < 4; ++j) {
            #pragma unroll
            for (int rr = 0; rr < 4; ++rr) {
                const int row = m0 + wm + i * 16 + quad * 4 + rr;
                const int col = n0 + wn + j * 16 + ln;
                out[(size_t)row * 256 + col] = acc[i][j][rr] + bo[col];
            }
        }
    }
}

// -------------------------------------------------------------------------
// attn: grid (1024 hs, 2). Each block stages V^T once and processes two qt
// tiles (qt = blockIdx.y*2 + iq). One 16-row m-tile per wave per qt.
// LDS = Vt 16.9K + Pl 9.7K + bmf 1K = 27.6KB -> LDS cap 5 blocks/CU.
// launch_bounds(256,2): arch-VGPR cap 128 (empirical: cap = 256/min_waves;
// 4 -> 64 and 5 -> 48 both spilled sc[16]). Body needs ~100 -> no spill,
// and 76..128 regs still yields 16 waves/CU = 4 blocks/CU = 50% occupancy.
// Pl is wave-private: P-write + PV-MFMA chunked over k in 4 phases of 64,
// relying on in-wave LDS ordering (same pattern the unchunked version used).
// Bias add reads the prep-permuted f32 bppf via coalesced float4 loads;
// identical values + add order -> bit-identical output.
// O aliases Qh: wave reads only its own 16 Q rows before writing them.
// -------------------------------------------------------------------------
__global__ __launch_bounds__(256, 2) void attn_kernel(
    const u16* __restrict__ Qh, const u16* __restrict__ Kh, const u16* __restrict__ Vh,
    const u16* __restrict__ Gh, const float* __restrict__ bm, const float* __restrict__ bppf,
    u16* __restrict__ Oh)
{
    __shared__ u16   Vt[32][264];       // V transposed: Vt[dh][kp]
    __shared__ u16   Pl[4][16][76];     // per-wave P chunk (k-width 64)
    __shared__ float bmf[256];

    const int hs   = blockIdx.x;
    const int h    = hs & 7;
    const int s    = hs >> 3;
    const int tid  = threadIdx.x;
    const int lane = tid & 63;
    const int w    = tid >> 6;
    const int quad = lane >> 4;
    const int ln   = lane & 15;

    const size_t hsBase = ((size_t)(h * 128 + s) * 256) << 5;   // start of [h][s] slice

    {   // stage V^T (thread tid = key row; 64 B/thread, block-contiguous 16 KB)
        const uint4* vp = (const uint4*)(Vh + hsBase + (size_t)tid * 32);
        uint4 vv0 = vp[0], vv1 = vp[1], vv2 = vp[2], vv3 = vp[3];
        u16 tmp[32];
        *(uint4*)&tmp[0]  = vv0; *(uint4*)&tmp[8]  = vv1;
        *(uint4*)&tmp[16] = vv2; *(uint4*)&tmp[24] = vv3;
        #pragma unroll
        for (int dh = 0; dh < 32; ++dh) Vt[dh][tid] = tmp[dh];
        bmf[tid] = bm[s * 256 + tid];
    }
    __syncthreads();

    for (int iq = 0; iq < 2; ++iq) {
        const int qt = blockIdx.y * 2 + iq;
        const int q0 = qt * 64 + w * 16;

        bf16x8 aq = __builtin_bit_cast(bf16x8,
            *(const uint4*)(Qh + hsBase + (size_t)(q0 + ln) * 32 + quad * 8));

        f32x4 sc[16];
        #pragma unroll
        for (int nt = 0; nt < 16; ++nt) {
            bf16x8 bk = __builtin_bit_cast(bf16x8,
                *(const uint4*)(Kh + hsBase + (size_t)(nt * 16 + ln) * 32 + quad * 8));
            f32x4 z = {0.f, 0.f, 0.f, 0.f};
            sc[nt] = __builtin_amdgcn_mfma_f32_16x16x32_bf16(aq, bk, z, 0, 0, 0);
        }

        // bias add from permuted bppf: float4 per nt holds rr=0..3 for this
        // lane's q rows at kp = nt*16+ln. Same f32 values & add order as before.
        const float* bpt = bppf + ((size_t)(((h * 4 + qt) * 4 + w) * 16) * 64 + lane) * 4;
        float rmax[4] = {-1e30f, -1e30f, -1e30f, -1e30f};
        #pragma unroll
        for (int nt = 0; nt < 16; ++nt) {
            const f32x4 bv = *(const f32x4*)(bpt + (size_t)nt * 256);
            const float bmv = bmf[nt * 16 + ln];
            #pragma unroll
            for (int rr = 0; rr < 4; ++rr) {
                float v = sc[nt][rr] + bmv + bv[rr];
                sc[nt][rr] = v;
                rmax[rr] = fmaxf(rmax[rr], v);
            }
        }
        #pragma unroll
        for (int rr = 0; rr < 4; ++rr) {
            float m = rmax[rr];
            m = fmaxf(m, __shfl_xor(m, 1));
            m = fmaxf(m, __shfl_xor(m, 2));
            m = fmaxf(m, __shfl_xor(m, 4));
            m = fmaxf(m, __shfl_xor(m, 8));
            rmax[rr] = m;
        }
        float rsum[4] = {0.f, 0.f, 0.f, 0.f};
        #pragma unroll
        for (int nt = 0; nt < 16; ++nt)
            #pragma unroll
            for (int rr = 0; rr < 4; ++rr) {
                float p = __expf(sc[nt][rr] - rmax[rr]);
                sc[nt][rr] = p;
                rsum[rr] += p;
            }
        float rinv[4];
        #pragma unroll
        for (int rr = 0; rr < 4; ++rr) {
            float t = rsum[rr];
            t += __shfl_xor(t, 1);
            t += __shfl_xor(t, 2);
            t += __shfl_xor(t, 4);
            t += __shfl_xor(t, 8);
            rinv[rr] = 1.0f / t;
        }

        // chunked P-write + PV (k ascending, same accumulation order as before)
        f32x4 o0 = {0.f, 0.f, 0.f, 0.f}, o1 = {0.f, 0.f, 0.f, 0.f};
        #pragma unroll
        for (int c = 0; c < 4; ++c) {
            #pragma unroll
            for (int ntl = 0; ntl < 4; ++ntl) {
                const int nt = c * 4 + ntl;
                #pragma unroll
                for (int rr = 0; rr < 4; ++rr)
                    Pl[w][quad * 4 + rr][ntl * 16 + ln] = f2bf(sc[nt][rr] * rinv[rr]);
            }
            #pragma unroll
            for (int kcl = 0; kcl < 2; ++kcl) {
                bf16x8 pa = __builtin_bit_cast(bf16x8, *(const uint4*)&Pl[w][ln][kcl * 32 + quad * 8]);
                bf16x8 v0 = __builtin_bit_cast(bf16x8, *(const uint4*)&Vt[ln][c * 64 + kcl * 32 + quad * 8]);
                bf16x8 v1 = __builtin_bit_cast(bf16x8, *(const uint4*)&Vt[16 + ln][c * 64 + kcl * 32 + quad * 8]);
                o0 = __builtin_amdgcn_mfma_f32_16x16x32_bf16(pa, v0, o0, 0, 0, 0);
                o1 = __builtin_amdgcn_mfma_f32_16x16x32_bf16(pa, v1, o1, 0, 0, 0);
            }
        }

        #pragma unroll
        for (int rr = 0; rr < 4; ++rr) {
            const int q = q0 + quad * 4 + rr;
            const size_t base = hsBase + (size_t)q * 32;
            float g0 = bf2f(Gh[base + ln]);
            float g1 = bf2f(Gh[base + 16 + ln]);
            Oh[base + ln]      = f2bf(o0[rr] * g0);
            Oh[base + 16 + ln] = f2bf(o1[rr] * g1);
        }
    }
}

// -------------------------------------------------------------------------
extern "C" void kernel_launch(void* const* d_in, const int* in_sizes, int n_in,
                              void* d_out, int out_size, void* d_ws, size_t ws_size,
                              hipStream_t stream)
{
    const float* qx  = (const float*)d_in[0];
    const float* kvx = (const float*)d_in[1];
    const float* bm  = (const float*)d_in[2];
    const float* bp  = (const float*)d_in[3];
    const float* Wq  = (const float*)d_in[4];
    const float* Wk  = (const float*)d_in[5];
    const float* Wv  = (const float*)d_in[6];
    const float* Wg  = (const float*)d_in[7];
    const float* bg  = (const float*)d_in[8];
    const float* Wo  = (const float*)d_in[9];
    const float* bo  = (const float*)d_in[10];
    float* out = (float*)d_out;

    // ws: Qh(=Oh), Kh, Vh, Gh (bf16, 16.78 MB each, head-major) + weights
    //     + permuted f32 bias_pair (2 MB). Total ~69.9 MB.
    const size_t NEL = (size_t)32768 * 256;
    u16* Qh = (u16*)d_ws;            // also Oh
    u16* Kh = Qh + NEL;
    u16* Vh = Kh + NEL;
    u16* Gh = Vh + NEL;
    u16* Wball = Gh + NEL;           // 5 * 65536 u16
    float* bppf = (float*)(Wball + 5 * 65536);   // 524288 f32

    // d_out doubles as bf16 scratch for qx/kvx; overwritten by gemm_out.
    u16* Xq  = (u16*)d_out;
    u16* Xkv = Xq + NEL;

    prep<<<dim3(8608), dim3(256), 0, stream>>>(qx, kvx, Wq, Wk, Wv, Wg, Wo, bp,
                                               Xq, Xkv, Wball, bppf);

    proj_all<<<dim3(2048), dim3(256), 0, stream>>>(Xq, Xkv, Wball, bg, Qh, Kh, Vh, Gh);

    attn_kernel<<<dim3(1024, 2), dim3(256), 0, stream>>>(Qh, Kh, Vh, Gh, bm, bppf, Qh /*Oh*/);

    gemm_out<<<dim3(1024), dim3(256), 0, stream>>>(Qh /*Oh*/, Wball + 4 * 65536, bo, out);
}

// Round 5
// 220.975 us; speedup vs baseline: 1.3572x; 1.0239x over previous
//
#include <hip/hip_runtime.h>

// Shapes: B=1, S=128, Q=256, C=256, H=8, DH=32, TOT=256. Inputs/out f32.
// Numerics: absmax 0.01953125 vs thr 0.019609 (bf16-quantization bound).
// R12: proj_all epilogue was 64 scalar 2-B stores/thread (~131K store
// instrs/CU vs 160K total cycles -> THE bottleneck; MfmaUtil 9.3%).
// Fix: swap MFMA operands (mfma(W,X) instead of mfma(X,W)) so the 4 acc
// regs hold 4 CONSECUTIVE dh (memory-contiguous in head-major) -> one 8-B
// packed store per acc = 16 stores/thread (4x fewer). Same swap in
// gemm_out -> 8 float4 stores/thread (64-B-line coalesced). Each output
// element still receives the identical k-ordered MFMA accumulation ->
// numerics unchanged. Attn keeps R8-R11 wins: LDS 27.6 KB, (256,2) VGPR
// cap 128 (cap = 256/min_waves; 4 and 5 spilled), permuted f32 bias,
// qt pairing.

typedef unsigned short u16;
typedef unsigned int   u32;
typedef float  f32x4  __attribute__((ext_vector_type(4)));
typedef __bf16 bf16x8 __attribute__((ext_vector_type(8)));

__device__ __forceinline__ float bf2f(u16 u) {
    union { u32 i; float f; } v; v.i = ((u32)u) << 16; return v.f;
}
__device__ __forceinline__ u16 f2bf(float f) {      // hw RNE cvt
    __bf16 h = (__bf16)f; return __builtin_bit_cast(u16, h);
}

// async global->LDS, 16B/lane; lds dest wave-uniform base (HW adds lane*16)
__device__ __forceinline__ void gld16(const u16* g, u16* l) {
    __builtin_amdgcn_global_load_lds(
        (const __attribute__((address_space(1))) u32*)g,
        (__attribute__((address_space(3))) u32*)l, 16, 0, 0);
}

// head-major offset for logical (row = s*256+q, col = h*32+dh)
__device__ __forceinline__ size_t hm(int row, int col) {
    const int s = row >> 8, q = row & 255, h = col >> 5, dh = col & 31;
    return ((size_t)((h * 128 + s) * 256 + q) << 5) + dh;
}

// -------------------------------------------------------------------------
// prep: f32 -> bf16 for qx, kvx (into d_out scratch) and the 5 weight mats,
// plus f32 permute of bias_pair into bppf[(h,qt,w)][nt][lane][rr].
// -------------------------------------------------------------------------
__device__ __forceinline__ void cvt8(const float4* src, u16* dst) {
    float4 a = src[0], b = src[1];
    u16 r[8];
    r[0] = f2bf(a.x); r[1] = f2bf(a.y); r[2] = f2bf(a.z); r[3] = f2bf(a.w);
    r[4] = f2bf(b.x); r[5] = f2bf(b.y); r[6] = f2bf(b.z); r[7] = f2bf(b.w);
    *(uint4*)dst = *(uint4*)r;
}

__global__ __launch_bounds__(256) void prep(
    const float* __restrict__ qx, const float* __restrict__ kvx,
    const float* __restrict__ Wq, const float* __restrict__ Wk,
    const float* __restrict__ Wv, const float* __restrict__ Wg,
    const float* __restrict__ Wo, const float* __restrict__ bp,
    u16* __restrict__ Xq, u16* __restrict__ Xkv, u16* __restrict__ Wball,
    float* __restrict__ bppf)
{
    const int b = blockIdx.x, t = threadIdx.x;
    if (b < 4096) {
        const int e = (b * 256 + t) * 8;
        cvt8((const float4*)(qx + e), Xq + e);
    } else if (b < 8192) {
        const int e = ((b - 4096) * 256 + t) * 8;
        cvt8((const float4*)(kvx + e), Xkv + e);
    } else if (b < 8352) {
        const int b2  = b - 8192;            // 0..159: 32 blocks per matrix
        const int mat = b2 >> 5;
        const float* W = (mat == 0) ? Wq : (mat == 1) ? Wk : (mat == 2) ? Wv
                       : (mat == 3) ? Wg : Wo;
        const int off = (b2 & 31) * 2048 + t * 8;
        cvt8((const float4*)(W + off), Wball + mat * 65536 + off);
    } else {
        // bias_pair permute: unit u = ((h*4+qt)*4+w)*16*64 + nt*64 + lane,
        // holds bp rows q0..q0+3 (rr in float4 lanes) at col kp.
        const int b3 = b - 8352;             // 0..255
        const int u0 = (b3 * 256 + t) * 2;
        #pragma unroll
        for (int k2 = 0; k2 < 2; ++k2) {
            const int u  = u0 + k2;
            const int l  = u & 63;
            const int nt = (u >> 6) & 15;
            const int tt = u >> 10;          // (h*4+qt)*4+w, 0..127
            const int ww = tt & 3, qqt = (tt >> 2) & 3, hh = tt >> 4;
            const int qb = qqt * 64 + ww * 16 + (l >> 4) * 4;
            const int kp = nt * 16 + (l & 15);
            const float* src = bp + (size_t)(hh * 256 + qb) * 256 + kp;
            float4 v;
            v.x = src[0]; v.y = src[256]; v.z = src[512]; v.w = src[768];
            *(float4*)(bppf + (size_t)u * 4) = v;
        }
    }
}

// -------------------------------------------------------------------------
// proj_all: fused Q/K/V/G projections, m97 structure. 2048 blocks.
// Block tile 128x128, BK=64, 4 waves 2x2, wave 64x64 (4x4 frags).
// Swizzle: mb = bid&255 -> 8 A-sharing siblings 256 apart == same XCD.
// MFMA operands SWAPPED (W as A-arg): D "row"(quad*4+rr) = n(dh),
// "col"(ln) = m(q) -> acc[i][j] is 4 consecutive dh -> one 8-B store.
// Output written HEAD-MAJOR via hm().
// -------------------------------------------------------------------------
__global__ __launch_bounds__(256) void proj_all(
    const u16* __restrict__ Xq, const u16* __restrict__ Xkv,
    const u16* __restrict__ Wball, const float* __restrict__ bg,
    u16* __restrict__ Qh, u16* __restrict__ Kh, u16* __restrict__ Vh, u16* __restrict__ Gh)
{
    __shared__ u16 At[128 * 64];     // unpadded: required by global_load_lds
    __shared__ u16 Wt[128 * 64];

    const int bid = blockIdx.x;
    const int mb  = bid & 255;
    const int nb  = bid >> 8;        // 0..7
    const int t   = nb >> 1;         // 0=Q 1=K 2=V 3=G
    const int n0  = (nb & 1) * 128;
    const int m0  = mb * 128;
    const u16* A = (t == 0 || t == 3) ? Xq : Xkv;
    const u16* W = Wball + t * 65536;
    u16*       O = (t == 0) ? Qh : (t == 1) ? Kh : (t == 2) ? Vh : Gh;

    const int tid  = threadIdx.x;
    const int lane = tid & 63;
    const int w    = tid >> 6;
    const int quad = lane >> 4;
    const int ln   = lane & 15;
    const int wm   = (w >> 1) * 64;
    const int wn   = (w & 1) * 64;
    const int lrow = lane >> 3;          // 0..7
    const int lcol = (lane & 7) * 8;     // u16 col

    f32x4 acc[4][4] = {};

    for (int k0 = 0; k0 < 256; k0 += 64) {
        __syncthreads();
        #pragma unroll
        for (int qq = 0; qq < 4; ++qq) {
            const int r = w * 32 + qq * 8;
            gld16(A + (size_t)(m0 + r + lrow) * 256 + k0 + lcol, &At[r * 64]);
            gld16(W + (size_t)(n0 + r + lrow) * 256 + k0 + lcol, &Wt[r * 64]);
        }
        __syncthreads();

        #pragma unroll
        for (int kk = 0; kk < 2; ++kk) {       // k ascending
            const int kc = kk * 32 + quad * 8;
            bf16x8 af[4], bfr[4];
            #pragma unroll
            for (int i = 0; i < 4; ++i)
                af[i] = __builtin_bit_cast(bf16x8, *(const uint4*)&At[(wm + i * 16 + ln) * 64 + kc]);
            #pragma unroll
            for (int j = 0; j < 4; ++j)
                bfr[j] = __builtin_bit_cast(bf16x8, *(const uint4*)&Wt[(wn + j * 16 + ln) * 64 + kc]);
            #pragma unroll
            for (int i = 0; i < 4; ++i)
                #pragma unroll
                for (int j = 0; j < 4; ++j)
                    acc[i][j] = __builtin_amdgcn_mfma_f32_16x16x32_bf16(bfr[j], af[i], acc[i][j], 0, 0, 0);
        }
    }

    const int act = (t == 3);
    #pragma unroll
    for (int i = 0; i < 4; ++i) {
        const int row = m0 + wm + i * 16 + ln;            // q-row (m)
        #pragma unroll
        for (int j = 0; j < 4; ++j) {
            const int colb = n0 + wn + j * 16 + quad * 4; // dh base (n), 4-aligned
            u16 r4[4];
            if (act) {
                const float4 bgv = *(const float4*)&bg[colb];
                float v0 = acc[i][j][0] + bgv.x;
                float v1 = acc[i][j][1] + bgv.y;
                float v2 = acc[i][j][2] + bgv.z;
                float v3 = acc[i][j][3] + bgv.w;
                r4[0] = f2bf(1.0f / (1.0f + __expf(-v0)));
                r4[1] = f2bf(1.0f / (1.0f + __expf(-v1)));
                r4[2] = f2bf(1.0f / (1.0f + __expf(-v2)));
                r4[3] = f2bf(1.0f / (1.0f + __expf(-v3)));
            } else {
                r4[0] = f2bf(acc[i][j][0]);
                r4[1] = f2bf(acc[i][j][1]);
                r4[2] = f2bf(acc[i][j][2]);
                r4[3] = f2bf(acc[i][j][3]);
            }
            *(uint2*)(O + hm(row, colb)) = *(const uint2*)r4;
        }
    }
}

// -------------------------------------------------------------------------
// gemm_out: out = O @ Wo^T + bo (f32 out). O is head-major (aliases Qh).
// BM=64 -> 1024 blocks. Swizzle: m fastest -> n-siblings 512 apart.
// MFMA operands swapped -> acc[i][j] = 4 consecutive cols -> float4 store.
// -------------------------------------------------------------------------
__global__ __launch_bounds__(256) void gemm_out(
    const u16* __restrict__ Oh, const u16* __restrict__ Wob,
    const float* __restrict__ bo, float* __restrict__ out)
{
    __shared__ u16 At[64 * 64];
    __shared__ u16 Wt[128 * 64];

    const int bid = blockIdx.x;
    const int m0  = (bid & 511) * 64;
    const int n0  = (bid >> 9) * 128;

    const int tid  = threadIdx.x;
    const int lane = tid & 63;
    const int w    = tid >> 6;
    const int quad = lane >> 4;
    const int ln   = lane & 15;
    const int wm   = (w >> 1) * 32;
    const int wn   = (w & 1) * 64;
    const int lrow = lane >> 3;
    const int lcol = (lane & 7) * 8;

    f32x4 acc[2][4] = {};

    for (int k0 = 0; k0 < 256; k0 += 64) {
        __syncthreads();
        #pragma unroll
        for (int qq = 0; qq < 2; ++qq) {
            const int r = w * 16 + qq * 8;
            // head-major A: per-lane address from (m, k)
            gld16(Oh + hm(m0 + r + lrow, k0 + lcol), &At[r * 64]);
        }
        #pragma unroll
        for (int qq = 0; qq < 4; ++qq) {
            const int r = w * 32 + qq * 8;
            gld16(Wob + (size_t)(n0 + r + lrow) * 256 + k0 + lcol, &Wt[r * 64]);
        }
        __syncthreads();

        #pragma unroll
        for (int kk = 0; kk < 2; ++kk) {
            const int kc = kk * 32 + quad * 8;
            bf16x8 af[2], bfr[4];
            #pragma unroll
            for (int i = 0; i < 2; ++i)
                af[i] = __builtin_bit_cast(bf16x8, *(const uint4*)&At[(wm + i * 16 + ln) * 64 + kc]);
            #pragma unroll
            for (int j = 0; j < 4; ++j)
                bfr[j] = __builtin_bit_cast(bf16x8, *(const uint4*)&Wt[(wn + j * 16 + ln) * 64 + kc]);
            #pragma unroll
            for (int i = 0; i < 2; ++i)
                #pragma unroll
                for (int j = 0; j < 4; ++j)
                    acc[i][j] = __builtin_amdgcn_mfma_f32_16x16x32_bf16(bfr[j], af[i], acc[i][j], 0, 0, 0);
        }
    }

    #pragma unroll
    for (int i = 0; i < 2; ++i) {
        const int row = m0 + wm + i * 16 + ln;
        #pragma unroll
        for (int j = 0; j < 4; ++j) {
            const int colb = n0 + wn + j * 16 + quad * 4;
            const float4 bov = *(const float4*)&bo[colb];
            float4 o;
            o.x = acc[i][j][0] + bov.x;
            o.y = acc[i][j][1] + bov.y;
            o.z = acc[i][j][2] + bov.z;
            o.w = acc[i][j][3] + bov.w;
            *(float4*)&out[(size_t)row * 256 + colb] = o;
        }
    }
}

// -------------------------------------------------------------------------
// attn: grid (1024 hs, 2). Each block stages V^T once and processes two qt
// tiles (qt = blockIdx.y*2 + iq). One 16-row m-tile per wave per qt.
// LDS = Vt 16.9K + Pl 9.7K + bmf 1K = 27.6KB -> LDS cap 5 blocks/CU.
// launch_bounds(256,2): arch-VGPR cap 128 (empirical: cap = 256/min_waves;
// 4 -> 64 and 5 -> 48 both spilled sc[16]). Body needs ~100 -> no spill,
// and 76..128 regs still yields 16 waves/CU = 4 blocks/CU = 50% occupancy.
// Pl is wave-private: P-write + PV-MFMA chunked over k in 4 phases of 64,
// relying on in-wave LDS ordering (same pattern the unchunked version used).
// Bias add reads the prep-permuted f32 bppf via coalesced float4 loads;
// identical values + add order -> bit-identical output.
// O aliases Qh: wave reads only its own 16 Q rows before writing them.
// -------------------------------------------------------------------------
__global__ __launch_bounds__(256, 2) void attn_kernel(
    const u16* __restrict__ Qh, const u16* __restrict__ Kh, const u16* __restrict__ Vh,
    const u16* __restrict__ Gh, const float* __restrict__ bm, const float* __restrict__ bppf,
    u16* __restrict__ Oh)
{
    __shared__ u16   Vt[32][264];       // V transposed: Vt[dh][kp]
    __shared__ u16   Pl[4][16][76];     // per-wave P chunk (k-width 64)
    __shared__ float bmf[256];

    const int hs   = blockIdx.x;
    const int h    = hs & 7;
    const int s    = hs >> 3;
    const int tid  = threadIdx.x;
    const int lane = tid & 63;
    const int w    = tid >> 6;
    const int quad = lane >> 4;
    const int ln   = lane & 15;

    const size_t hsBase = ((size_t)(h * 128 + s) * 256) << 5;   // start of [h][s] slice

    {   // stage V^T (thread tid = key row; 64 B/thread, block-contiguous 16 KB)
        const uint4* vp = (const uint4*)(Vh + hsBase + (size_t)tid * 32);
        uint4 vv0 = vp[0], vv1 = vp[1], vv2 = vp[2], vv3 = vp[3];
        u16 tmp[32];
        *(uint4*)&tmp[0]  = vv0; *(uint4*)&tmp[8]  = vv1;
        *(uint4*)&tmp[16] = vv2; *(uint4*)&tmp[24] = vv3;
        #pragma unroll
        for (int dh = 0; dh < 32; ++dh) Vt[dh][tid] = tmp[dh];
        bmf[tid] = bm[s * 256 + tid];
    }
    __syncthreads();

    for (int iq = 0; iq < 2; ++iq) {
        const int qt = blockIdx.y * 2 + iq;
        const int q0 = qt * 64 + w * 16;

        bf16x8 aq = __builtin_bit_cast(bf16x8,
            *(const uint4*)(Qh + hsBase + (size_t)(q0 + ln) * 32 + quad * 8));

        f32x4 sc[16];
        #pragma unroll
        for (int nt = 0; nt < 16; ++nt) {
            bf16x8 bk = __builtin_bit_cast(bf16x8,
                *(const uint4*)(Kh + hsBase + (size_t)(nt * 16 + ln) * 32 + quad * 8));
            f32x4 z = {0.f, 0.f, 0.f, 0.f};
            sc[nt] = __builtin_amdgcn_mfma_f32_16x16x32_bf16(aq, bk, z, 0, 0, 0);
        }

        // bias add from permuted bppf: float4 per nt holds rr=0..3 for this
        // lane's q rows at kp = nt*16+ln. Same f32 values & add order as before.
        const float* bpt = bppf + ((size_t)(((h * 4 + qt) * 4 + w) * 16) * 64 + lane) * 4;
        float rmax[4] = {-1e30f, -1e30f, -1e30f, -1e30f};
        #pragma unroll
        for (int nt = 0; nt < 16; ++nt) {
            const f32x4 bv = *(const f32x4*)(bpt + (size_t)nt * 256);
            const float bmv = bmf[nt * 16 + ln];
            #pragma unroll
            for (int rr = 0; rr < 4; ++rr) {
                float v = sc[nt][rr] + bmv + bv[rr];
                sc[nt][rr] = v;
                rmax[rr] = fmaxf(rmax[rr], v);
            }
        }
        #pragma unroll
        for (int rr = 0; rr < 4; ++rr) {
            float m = rmax[rr];
            m = fmaxf(m, __shfl_xor(m, 1));
            m = fmaxf(m, __shfl_xor(m, 2));
            m = fmaxf(m, __shfl_xor(m, 4));
            m = fmaxf(m, __shfl_xor(m, 8));
            rmax[rr] = m;
        }
        float rsum[4] = {0.f, 0.f, 0.f, 0.f};
        #pragma unroll
        for (int nt = 0; nt < 16; ++nt)
            #pragma unroll
            for (int rr = 0; rr < 4; ++rr) {
                float p = __expf(sc[nt][rr] - rmax[rr]);
                sc[nt][rr] = p;
                rsum[rr] += p;
            }
        float rinv[4];
        #pragma unroll
        for (int rr = 0; rr < 4; ++rr) {
            float t = rsum[rr];
            t += __shfl_xor(t, 1);
            t += __shfl_xor(t, 2);
            t += __shfl_xor(t, 4);
            t += __shfl_xor(t, 8);
            rinv[rr] = 1.0f / t;
        }

        // chunked P-write + PV (k ascending, same accumulation order as before)
        f32x4 o0 = {0.f, 0.f, 0.f, 0.f}, o1 = {0.f, 0.f, 0.f, 0.f};
        #pragma unroll
        for (int c = 0; c < 4; ++c) {
            #pragma unroll
            for (int ntl = 0; ntl < 4; ++ntl) {
                const int nt = c * 4 + ntl;
                #pragma unroll
                for (int rr = 0; rr < 4; ++rr)
                    Pl[w][quad * 4 + rr][ntl * 16 + ln] = f2bf(sc[nt][rr] * rinv[rr]);
            }
            #pragma unroll
            for (int kcl = 0; kcl < 2; ++kcl) {
                bf16x8 pa = __builtin_bit_cast(bf16x8, *(const uint4*)&Pl[w][ln][kcl * 32 + quad * 8]);
                bf16x8 v0 = __builtin_bit_cast(bf16x8, *(const uint4*)&Vt[ln][c * 64 + kcl * 32 + quad * 8]);
                bf16x8 v1 = __builtin_bit_cast(bf16x8, *(const uint4*)&Vt[16 + ln][c * 64 + kcl * 32 + quad * 8]);
                o0 = __builtin_amdgcn_mfma_f32_16x16x32_bf16(pa, v0, o0, 0, 0, 0);
                o1 = __builtin_amdgcn_mfma_f32_16x16x32_bf16(pa, v1, o1, 0, 0, 0);
            }
        }

        #pragma unroll
        for (int rr = 0; rr < 4; ++rr) {
            const int q = q0 + quad * 4 + rr;
            const size_t base = hsBase + (size_t)q * 32;
            float g0 = bf2f(Gh[base + ln]);
            float g1 = bf2f(Gh[base + 16 + ln]);
            Oh[base + ln]      = f2bf(o0[rr] * g0);
            Oh[base + 16 + ln] = f2bf(o1[rr] * g1);
        }
    }
}

// -------------------------------------------------------------------------
extern "C" void kernel_launch(void* const* d_in, const int* in_sizes, int n_in,
                              void* d_out, int out_size, void* d_ws, size_t ws_size,
                              hipStream_t stream)
{
    const float* qx  = (const float*)d_in[0];
    const float* kvx = (const float*)d_in[1];
    const float* bm  = (const float*)d_in[2];
    const float* bp  = (const float*)d_in[3];
    const float* Wq  = (const float*)d_in[4];
    const float* Wk  = (const float*)d_in[5];
    const float* Wv  = (const float*)d_in[6];
    const float* Wg  = (const float*)d_in[7];
    const float* bg  = (const float*)d_in[8];
    const float* Wo  = (const float*)d_in[9];
    const float* bo  = (const float*)d_in[10];
    float* out = (float*)d_out;

    // ws: Qh(=Oh), Kh, Vh, Gh (bf16, 16.78 MB each, head-major) + weights
    //     + permuted f32 bias_pair (2 MB). Total ~69.9 MB.
    const size_t NEL = (size_t)32768 * 256;
    u16* Qh = (u16*)d_ws;            // also Oh
    u16* Kh = Qh + NEL;
    u16* Vh = Kh + NEL;
    u16* Gh = Vh + NEL;
    u16* Wball = Gh + NEL;           // 5 * 65536 u16
    float* bppf = (float*)(Wball + 5 * 65536);   // 524288 f32

    // d_out doubles as bf16 scratch for qx/kvx; overwritten by gemm_out.
    u16* Xq  = (u16*)d_out;
    u16* Xkv = Xq + NEL;

    prep<<<dim3(8608), dim3(256), 0, stream>>>(qx, kvx, Wq, Wk, Wv, Wg, Wo, bp,
                                               Xq, Xkv, Wball, bppf);

    proj_all<<<dim3(2048), dim3(256), 0, stream>>>(Xq, Xkv, Wball, bg, Qh, Kh, Vh, Gh);

    attn_kernel<<<dim3(1024, 2), dim3(256), 0, stream>>>(Qh, Kh, Vh, Gh, bm, bppf, Qh /*Oh*/);

    gemm_out<<<dim3(1024), dim3(256), 0, stream>>>(Qh /*Oh*/, Wball + 4 * 65536, bo, out);
}